// Round 1
// baseline (5037.006 us; speedup 1.0000x reference)
//
#include <hip/hip_runtime.h>
#include <hip/hip_bf16.h>

typedef __attribute__((ext_vector_type(8))) short bf16x8;
typedef __attribute__((ext_vector_type(4))) float f32x4;

__device__ inline unsigned short f2bf(float f) {
    union { float f; unsigned u; } v; v.f = f;
    unsigned r = v.u + 0x7fff + ((v.u >> 16) & 1);   // RNE
    return (unsigned short)(r >> 16);
}

// One wave per edge: gather h[src] (1KB, 64 lanes x float4), atomic-add into sum[dst].
__global__ void scatter_kernel(const float* __restrict__ h,
                               const int* __restrict__ eidx, int E,
                               float* __restrict__ sum, float* __restrict__ cnt) {
    long gid = (long)blockIdx.x * blockDim.x + threadIdx.x;
    int e = (int)(gid >> 6);
    int lane = (int)(gid & 63);
    if (e >= E) return;
    int s = eidx[e];
    int d = eidx[E + e];
    const float4 v = *(const float4*)(h + (size_t)s * 256 + lane * 4);
    float* dp = sum + (size_t)d * 256 + lane * 4;
    unsafeAtomicAdd(dp + 0, v.x);
    unsafeAtomicAdd(dp + 1, v.y);
    unsafeAtomicAdd(dp + 2, v.z);
    unsafeAtomicAdd(dp + 3, v.w);
    if (lane == 0) unsafeAtomicAdd(cnt + d, 1.0f);
}

// Build X[Mpad][512] bf16 = [ mean | h_dst ], zero pad rows. One block per row.
__global__ void pack_kernel(const float* __restrict__ sum, const float* __restrict__ cnt,
                            const float* __restrict__ h, int M, int Mpad,
                            unsigned short* __restrict__ X) {
    int i = blockIdx.x;
    int c = threadIdx.x;
    unsigned short a = 0, b = 0;
    if (i < M) {
        float cn = cnt[i];
        float m = sum[(size_t)i * 256 + c] / fmaxf(cn, 1.0f);
        a = f2bf(m);
        b = f2bf(h[(size_t)i * 256 + c]);
    }
    X[(size_t)i * 512 + c] = a;
    X[(size_t)i * 512 + 256 + c] = b;
}

// Repack [W_l;W_r] (fp32, row-major [512][256] concat) into bf16 fragment layout
// Wsw[kb][col][e]  (kb = k/8, e = k%8)  so a B-fragment is one 16B load.
__global__ void convw_kernel(const float* __restrict__ Wl0, const float* __restrict__ Wr0,
                             const float* __restrict__ Wl1, const float* __restrict__ Wr1,
                             const float* __restrict__ Wl2, const float* __restrict__ Wr2,
                             unsigned short* __restrict__ Wsw) {
    int gid = blockIdx.x * blockDim.x + threadIdx.x;   // 3 * 512 * 256
    int l = gid >> 17;
    int r = gid & 131071;
    int k = r >> 8, c = r & 255;
    const float* W;
    if (k < 256) W = (l == 0) ? Wl0 : (l == 1) ? Wl1 : Wl2;
    else         W = (l == 0) ? Wr0 : (l == 1) ? Wr1 : Wr2;
    float v = W[(size_t)(k & 255) * 256 + c];
    Wsw[(size_t)l * 131072 + (size_t)(k >> 3) * 2048 + c * 8 + (k & 7)] = f2bf(v);
}

// out[M][256] = X[M][512] @ Wcat[512][256] + bias, optional ReLU.
// Block = 256 thr = 4 waves; block tile 64(M) x 64(N); wave tile 16(M) x 64(N).
__global__ void gemm_kernel(const unsigned short* __restrict__ X,
                            const unsigned short* __restrict__ Wsw,
                            const float* __restrict__ bias,
                            float* __restrict__ out, int M, int relu) {
    int tid = threadIdx.x;
    int wid = tid >> 6, lane = tid & 63;
    int lr = lane & 15, lg = lane >> 4;       // frag row / k-group
    int r0 = blockIdx.x * 64 + wid * 16;
    int c0 = blockIdx.y * 64;
    f32x4 acc[4] = {};
    const unsigned short* xp = X + (size_t)(r0 + lr) * 512 + lg * 8;
    #pragma unroll
    for (int k0 = 0; k0 < 512; k0 += 32) {
        bf16x8 a = *(const bf16x8*)(xp + k0);
        const unsigned short* wp = Wsw + ((size_t)(k0 >> 3) + lg) * 2048 + (size_t)(c0 + lr) * 8;
        #pragma unroll
        for (int nf = 0; nf < 4; ++nf) {
            bf16x8 b = *(const bf16x8*)(wp + (size_t)nf * 128);
            acc[nf] = __builtin_amdgcn_mfma_f32_16x16x32_bf16(a, b, acc[nf], 0, 0, 0);
        }
    }
    #pragma unroll
    for (int nf = 0; nf < 4; ++nf) {
        int col = c0 + nf * 16 + lr;
        float bv = bias[col];
        #pragma unroll
        for (int j = 0; j < 4; ++j) {
            int row = r0 + lg * 4 + j;
            if (row < M) {
                float v = acc[nf][j] + bv;
                if (relu) v = fmaxf(v, 0.0f);
                out[(size_t)row * 256 + col] = v;
            }
        }
    }
}

extern "C" void kernel_launch(void* const* d_in, const int* in_sizes, int n_in,
                              void* d_out, int out_size, void* d_ws, size_t ws_size,
                              hipStream_t stream) {
    const float* x  = (const float*)d_in[0];
    const int*   e0 = (const int*)d_in[1];
    const int*   e1 = (const int*)d_in[2];
    const int*   e2 = (const int*)d_in[3];
    const float* Wl[3] = {(const float*)d_in[4], (const float*)d_in[7], (const float*)d_in[10]};
    const float* bl[3] = {(const float*)d_in[5], (const float*)d_in[8], (const float*)d_in[11]};
    const float* Wr[3] = {(const float*)d_in[6], (const float*)d_in[9], (const float*)d_in[12]};
    float* out = (float*)d_out;

    char* ws = (char*)d_ws;
    float*          sum = (float*)(ws + 0);                    // 51,200,000 B
    float*          cnt = (float*)(ws + 51200000);             //    200,000 B
    unsigned short* X   = (unsigned short*)(ws + 51400192);    // 51,249,152 B (50048*512*2)
    float*          h1  = (float*)(ws + 102649344);            // 51,200,000 B
    float*          h2  = (float*)(ws + 153849344);            // 25,600,000 B
    unsigned short* Wsw = (unsigned short*)(ws + 179449344);   //    786,432 B

    const int Ns[4] = {100000, 50000, 25000, 12500};
    const int Es[3] = {800000, 400000, 200000};
    const int* eidx[3] = {e0, e1, e2};
    const float* hsrc[3] = {x, h1, h2};
    float* hdst[3] = {h1, h2, out};

    convw_kernel<<<1536, 256, 0, stream>>>(Wl[0], Wr[0], Wl[1], Wr[1], Wl[2], Wr[2], Wsw);

    for (int l = 0; l < 3; ++l) {
        int Md = Ns[l + 1], E = Es[l];
        int Mpad = (Md + 63) & ~63;
        hipMemsetAsync(sum, 0, (size_t)Md * 256 * 4, stream);
        hipMemsetAsync(cnt, 0, (size_t)Md * 4, stream);
        long sthreads = (long)E * 64;
        int sblocks = (int)((sthreads + 255) / 256);
        scatter_kernel<<<sblocks, 256, 0, stream>>>(hsrc[l], eidx[l], E, sum, cnt);
        pack_kernel<<<Mpad, 256, 0, stream>>>(sum, cnt, hsrc[l], Md, Mpad, X);
        gemm_kernel<<<dim3(Mpad / 64, 4), 256, 0, stream>>>(
            X, Wsw + (size_t)l * 131072, bl[l], hdst[l], Md, (l < 2) ? 1 : 0);
    }
}

// Round 2
// 801.316 us; speedup vs baseline: 6.2859x; 6.2859x over previous
//
#include <hip/hip_runtime.h>
#include <hip/hip_bf16.h>

typedef __attribute__((ext_vector_type(8))) short bf16x8;
typedef __attribute__((ext_vector_type(4))) float f32x4;

__device__ inline unsigned short f2bf(float f) {
    union { float f; unsigned u; } v; v.f = f;
    unsigned r = v.u + 0x7fff + ((v.u >> 16) & 1);   // RNE
    return (unsigned short)(r >> 16);
}

// --- CSR build ---------------------------------------------------------------

__global__ void hist_kernel(const int* __restrict__ eidx, int E, int* __restrict__ cnt) {
    int e = blockIdx.x * blockDim.x + threadIdx.x;
    if (e >= E) return;
    atomicAdd(&cnt[eidx[E + e]], 1);
}

// Single-block exclusive scan: cnt[0..M) -> rowptr[0..M], cursor = copy.
__global__ void scan_kernel(const int* __restrict__ cnt, int* __restrict__ rowptr,
                            int* __restrict__ cursor, int M, int E) {
    __shared__ int sdata[1024];
    __shared__ int carry_s;
    if (threadIdx.x == 0) carry_s = 0;
    __syncthreads();
    for (int base = 0; base < M; base += 1024) {
        int i = base + threadIdx.x;
        int v = (i < M) ? cnt[i] : 0;
        sdata[threadIdx.x] = v;
        __syncthreads();
        #pragma unroll
        for (int off = 1; off < 1024; off <<= 1) {
            int t = (threadIdx.x >= off) ? sdata[threadIdx.x - off] : 0;
            __syncthreads();
            sdata[threadIdx.x] += t;
            __syncthreads();
        }
        int excl = carry_s + sdata[threadIdx.x] - v;
        if (i < M) { rowptr[i] = excl; cursor[i] = excl; }
        __syncthreads();
        if (threadIdx.x == 0) carry_s += sdata[1023];
        __syncthreads();
    }
    if (threadIdx.x == 0) rowptr[M] = E;
}

__global__ void fill_kernel(const int* __restrict__ eidx, int E,
                            int* __restrict__ cursor, int* __restrict__ eids) {
    int e = blockIdx.x * blockDim.x + threadIdx.x;
    if (e >= E) return;
    int d = eidx[E + e];
    int pos = atomicAdd(&cursor[d], 1);
    eids[pos] = eidx[e];
}

// --- Aggregate (mean over CSR neighbors) + bf16 pack of [mean | h_dst] -------
// One wave per dst row; 64 lanes x float4 = full 256-col row.
__global__ void agg_pack_kernel(const float* __restrict__ h,
                                const int* __restrict__ rowptr,
                                const int* __restrict__ eids,
                                int M, int Mpad,
                                unsigned short* __restrict__ X) {
    int lane = threadIdx.x & 63;
    int row = blockIdx.x * (blockDim.x >> 6) + (threadIdx.x >> 6);
    if (row >= Mpad) return;
    ushort4* Xv = (ushort4*)X;
    if (row >= M) {
        ushort4 z = {0, 0, 0, 0};
        Xv[(size_t)row * 128 + lane] = z;
        Xv[(size_t)row * 128 + 64 + lane] = z;
        return;
    }
    const size_t loff = (size_t)lane * 4;
    int beg = rowptr[row], end = rowptr[row + 1];
    float a0 = 0, a1 = 0, a2 = 0, a3 = 0;   // two accumulators for ILP
    float b0 = 0, b1 = 0, b2 = 0, b3 = 0;
    int j = beg;
    for (; j + 2 <= end; j += 2) {
        const float4 v0 = *(const float4*)(h + (size_t)eids[j]     * 256 + loff);
        const float4 v1 = *(const float4*)(h + (size_t)eids[j + 1] * 256 + loff);
        a0 += v0.x; a1 += v0.y; a2 += v0.z; a3 += v0.w;
        b0 += v1.x; b1 += v1.y; b2 += v1.z; b3 += v1.w;
    }
    if (j < end) {
        const float4 v0 = *(const float4*)(h + (size_t)eids[j] * 256 + loff);
        a0 += v0.x; a1 += v0.y; a2 += v0.z; a3 += v0.w;
    }
    float inv = 1.0f / fmaxf((float)(end - beg), 1.0f);
    const float4 hd = *(const float4*)(h + (size_t)row * 256 + loff);
    ushort4 m, hh;
    m.x = f2bf((a0 + b0) * inv); m.y = f2bf((a1 + b1) * inv);
    m.z = f2bf((a2 + b2) * inv); m.w = f2bf((a3 + b3) * inv);
    hh.x = f2bf(hd.x); hh.y = f2bf(hd.y); hh.z = f2bf(hd.z); hh.w = f2bf(hd.w);
    Xv[(size_t)row * 128 + lane] = m;
    Xv[(size_t)row * 128 + 64 + lane] = hh;
}

// Repack [W_l;W_r] (fp32, row-major [512][256] concat) into bf16 fragment layout
// Wsw[kb][col][e]  (kb = k/8, e = k%8)  so a B-fragment is one 16B load.
__global__ void convw_kernel(const float* __restrict__ Wl0, const float* __restrict__ Wr0,
                             const float* __restrict__ Wl1, const float* __restrict__ Wr1,
                             const float* __restrict__ Wl2, const float* __restrict__ Wr2,
                             unsigned short* __restrict__ Wsw) {
    int gid = blockIdx.x * blockDim.x + threadIdx.x;   // 3 * 512 * 256
    int l = gid >> 17;
    int r = gid & 131071;
    int k = r >> 8, c = r & 255;
    const float* W;
    if (k < 256) W = (l == 0) ? Wl0 : (l == 1) ? Wl1 : Wl2;
    else         W = (l == 0) ? Wr0 : (l == 1) ? Wr1 : Wr2;
    float v = W[(size_t)(k & 255) * 256 + c];
    Wsw[(size_t)l * 131072 + (size_t)(k >> 3) * 2048 + c * 8 + (k & 7)] = f2bf(v);
}

// out[M][256] = X[M][512] @ Wcat[512][256] + bias, optional ReLU.
// Block = 256 thr = 4 waves; block tile 64(M) x 64(N); wave tile 16(M) x 64(N).
__global__ void gemm_kernel(const unsigned short* __restrict__ X,
                            const unsigned short* __restrict__ Wsw,
                            const float* __restrict__ bias,
                            float* __restrict__ out, int M, int relu) {
    int tid = threadIdx.x;
    int wid = tid >> 6, lane = tid & 63;
    int lr = lane & 15, lg = lane >> 4;       // frag row / k-group
    int r0 = blockIdx.x * 64 + wid * 16;
    int c0 = blockIdx.y * 64;
    f32x4 acc[4] = {};
    const unsigned short* xp = X + (size_t)(r0 + lr) * 512 + lg * 8;
    #pragma unroll
    for (int k0 = 0; k0 < 512; k0 += 32) {
        bf16x8 a = *(const bf16x8*)(xp + k0);
        const unsigned short* wp = Wsw + ((size_t)(k0 >> 3) + lg) * 2048 + (size_t)(c0 + lr) * 8;
        #pragma unroll
        for (int nf = 0; nf < 4; ++nf) {
            bf16x8 b = *(const bf16x8*)(wp + (size_t)nf * 128);
            acc[nf] = __builtin_amdgcn_mfma_f32_16x16x32_bf16(a, b, acc[nf], 0, 0, 0);
        }
    }
    #pragma unroll
    for (int nf = 0; nf < 4; ++nf) {
        int col = c0 + nf * 16 + lr;
        float bv = bias[col];
        #pragma unroll
        for (int j = 0; j < 4; ++j) {
            int row = r0 + lg * 4 + j;
            if (row < M) {
                float v = acc[nf][j] + bv;
                if (relu) v = fmaxf(v, 0.0f);
                out[(size_t)row * 256 + col] = v;
            }
        }
    }
}

extern "C" void kernel_launch(void* const* d_in, const int* in_sizes, int n_in,
                              void* d_out, int out_size, void* d_ws, size_t ws_size,
                              hipStream_t stream) {
    const float* x  = (const float*)d_in[0];
    const int*   e0 = (const int*)d_in[1];
    const int*   e1 = (const int*)d_in[2];
    const int*   e2 = (const int*)d_in[3];
    const float* Wl[3] = {(const float*)d_in[4], (const float*)d_in[7], (const float*)d_in[10]};
    const float* bl[3] = {(const float*)d_in[5], (const float*)d_in[8], (const float*)d_in[11]};
    const float* Wr[3] = {(const float*)d_in[6], (const float*)d_in[9], (const float*)d_in[12]};
    float* out = (float*)d_out;

    char* ws = (char*)d_ws;
    unsigned short* X      = (unsigned short*)(ws + 0);            // 50048*512*2 = 51,249,152
    float*          h1     = (float*)(ws + 51249152);              // 50000*256*4 = 51,200,000
    float*          h2     = (float*)(ws + 102449152);             // 25000*256*4 = 25,600,000
    unsigned short* Wsw    = (unsigned short*)(ws + 128049152);    // 3*512*256*2 =    786,432
    int*            cnt    = (int*)(ws + 128835584);               //    200,192
    int*            rowptr = (int*)(ws + 129035776);               //    200,192
    int*            cursor = (int*)(ws + 129235968);               //    200,192
    int*            eids   = (int*)(ws + 129436160);               //  3,200,000

    const int Ns[4] = {100000, 50000, 25000, 12500};
    const int Es[3] = {800000, 400000, 200000};
    const int* eidx[3] = {e0, e1, e2};
    const float* hsrc[3] = {x, h1, h2};
    float* hdst[3] = {h1, h2, out};

    convw_kernel<<<1536, 256, 0, stream>>>(Wl[0], Wr[0], Wl[1], Wr[1], Wl[2], Wr[2], Wsw);

    for (int l = 0; l < 3; ++l) {
        int Md = Ns[l + 1], E = Es[l];
        int Mpad = (Md + 63) & ~63;
        int eb = (E + 255) / 256;
        hipMemsetAsync(cnt, 0, (size_t)Md * 4, stream);
        hist_kernel<<<eb, 256, 0, stream>>>(eidx[l], E, cnt);
        scan_kernel<<<1, 1024, 0, stream>>>(cnt, rowptr, cursor, Md, E);
        fill_kernel<<<eb, 256, 0, stream>>>(eidx[l], E, cursor, eids);
        agg_pack_kernel<<<Mpad / 4, 256, 0, stream>>>(hsrc[l], rowptr, eids, Md, Mpad, X);
        gemm_kernel<<<dim3(Mpad / 64, 4), 256, 0, stream>>>(
            X, Wsw + (size_t)l * 131072, bl[l], hdst[l], Md, (l < 2) ? 1 : 0);
    }
}

// Round 3
// 760.213 us; speedup vs baseline: 6.6258x; 1.0541x over previous
//
#include <hip/hip_runtime.h>
#include <hip/hip_bf16.h>

typedef __attribute__((ext_vector_type(8))) short bf16x8;
typedef __attribute__((ext_vector_type(4))) float f32x4;

__device__ inline unsigned short f2bf(float f) {
    union { float f; unsigned u; } v; v.f = f;
    unsigned r = v.u + 0x7fff + ((v.u >> 16) & 1);   // RNE
    return (unsigned short)(r >> 16);
}
__device__ inline float bf2f(unsigned short u) {
    union { unsigned u; float f; } v; v.u = (unsigned)u << 16;
    return v.f;
}

// fp32 -> bf16 bulk convert (x -> xb), float4/thread.
__global__ void cvt_kernel(const float* __restrict__ x, unsigned short* __restrict__ xb, int n4) {
    int i = blockIdx.x * blockDim.x + threadIdx.x;
    if (i >= n4) return;
    float4 v = ((const float4*)x)[i];
    ushort4 o = { f2bf(v.x), f2bf(v.y), f2bf(v.z), f2bf(v.w) };
    ((ushort4*)xb)[i] = o;
}

// --- CSR build ---------------------------------------------------------------

__global__ void hist_kernel(const int* __restrict__ eidx, int E, int* __restrict__ cnt) {
    int e = blockIdx.x * blockDim.x + threadIdx.x;
    if (e >= E) return;
    atomicAdd(&cnt[eidx[E + e]], 1);
}

// One block, 1024 threads: each thread serially scans a contiguous chunk,
// single LDS scan of per-thread sums, re-walk to emit exclusive prefix.
__global__ void scan_kernel(const int* __restrict__ cnt, int* __restrict__ rowptr,
                            int* __restrict__ cursor, int M, int E) {
    __shared__ int sh[1024];
    int t = threadIdx.x;
    int C = (M + 1023) >> 10;
    int beg = t * C, end = min(beg + C, M);
    int s = 0;
    for (int i = beg; i < end; ++i) s += cnt[i];
    sh[t] = s;
    __syncthreads();
    #pragma unroll
    for (int off = 1; off < 1024; off <<= 1) {
        int v = (t >= off) ? sh[t - off] : 0;
        __syncthreads();
        sh[t] += v;
        __syncthreads();
    }
    int run = sh[t] - s;   // exclusive prefix of this thread's chunk
    for (int i = beg; i < end; ++i) {
        int c = cnt[i];
        rowptr[i] = run; cursor[i] = run;
        run += c;
    }
    if (t == 0) rowptr[M] = E;
}

__global__ void fill_kernel(const int* __restrict__ eidx, int E,
                            int* __restrict__ cursor, int* __restrict__ eids) {
    int e = blockIdx.x * blockDim.x + threadIdx.x;
    if (e >= E) return;
    int d = eidx[E + e];
    int pos = atomicAdd(&cursor[d], 1);
    eids[pos] = eidx[e];
}

// --- Aggregate (mean over CSR neighbors, bf16 rows) + pack [mean | h_dst] ----
// One wave per dst row; 64 lanes x ushort4 (8B) = full 256-col bf16 row.
__global__ void agg_pack_kernel(const unsigned short* __restrict__ hb,
                                const int* __restrict__ rowptr,
                                const int* __restrict__ eids,
                                int M, int Mpad,
                                unsigned short* __restrict__ X) {
    int lane = threadIdx.x & 63;
    int row = blockIdx.x * (blockDim.x >> 6) + (threadIdx.x >> 6);
    if (row >= Mpad) return;
    ushort4* Xv = (ushort4*)X;
    const ushort4* hv = (const ushort4*)hb;
    if (row >= M) {
        ushort4 z = {0, 0, 0, 0};
        Xv[(size_t)row * 128 + lane] = z;
        Xv[(size_t)row * 128 + 64 + lane] = z;
        return;
    }
    int beg = rowptr[row], end = rowptr[row + 1];
    float a0 = 0, a1 = 0, a2 = 0, a3 = 0;
    float b0 = 0, b1 = 0, b2 = 0, b3 = 0;
    int j = beg;
    for (; j + 4 <= end; j += 4) {
        int i0 = eids[j], i1 = eids[j + 1], i2 = eids[j + 2], i3 = eids[j + 3];
        ushort4 v0 = hv[(size_t)i0 * 64 + lane];
        ushort4 v1 = hv[(size_t)i1 * 64 + lane];
        ushort4 v2 = hv[(size_t)i2 * 64 + lane];
        ushort4 v3 = hv[(size_t)i3 * 64 + lane];
        a0 += bf2f(v0.x) + bf2f(v2.x); a1 += bf2f(v0.y) + bf2f(v2.y);
        a2 += bf2f(v0.z) + bf2f(v2.z); a3 += bf2f(v0.w) + bf2f(v2.w);
        b0 += bf2f(v1.x) + bf2f(v3.x); b1 += bf2f(v1.y) + bf2f(v3.y);
        b2 += bf2f(v1.z) + bf2f(v3.z); b3 += bf2f(v1.w) + bf2f(v3.w);
    }
    for (; j < end; ++j) {
        ushort4 v = hv[(size_t)eids[j] * 64 + lane];
        a0 += bf2f(v.x); a1 += bf2f(v.y); a2 += bf2f(v.z); a3 += bf2f(v.w);
    }
    float inv = 1.0f / fmaxf((float)(end - beg), 1.0f);
    ushort4 m;
    m.x = f2bf((a0 + b0) * inv); m.y = f2bf((a1 + b1) * inv);
    m.z = f2bf((a2 + b2) * inv); m.w = f2bf((a3 + b3) * inv);
    Xv[(size_t)row * 128 + lane] = m;
    Xv[(size_t)row * 128 + 64 + lane] = hv[(size_t)row * 64 + lane];
}

// Repack [W_l;W_r] (fp32 [512][256] concat) -> bf16 fragment layout
// Wsw[kb][col][e]  (kb = k/8, e = k%8): a B-fragment is one 16B load.
__global__ void convw_kernel(const float* __restrict__ Wl0, const float* __restrict__ Wr0,
                             const float* __restrict__ Wl1, const float* __restrict__ Wr1,
                             const float* __restrict__ Wl2, const float* __restrict__ Wr2,
                             unsigned short* __restrict__ Wsw) {
    int gid = blockIdx.x * blockDim.x + threadIdx.x;   // 3 * 512 * 256
    int l = gid >> 17;
    int r = gid & 131071;
    int k = r >> 8, c = r & 255;
    const float* W;
    if (k < 256) W = (l == 0) ? Wl0 : (l == 1) ? Wl1 : Wl2;
    else         W = (l == 0) ? Wr0 : (l == 1) ? Wr1 : Wr2;
    float v = W[(size_t)(k & 255) * 256 + c];
    Wsw[(size_t)l * 131072 + (size_t)(k >> 3) * 2048 + c * 8 + (k & 7)] = f2bf(v);
}

// out[M][256] = X[M][512] @ Wcat[512][256] + bias (+ReLU).
// Block 256 thr = 4 waves; block tile 64(M) x 256(N); wave tile 64 x 64.
__global__ void gemm_kernel(const unsigned short* __restrict__ X,
                            const unsigned short* __restrict__ Wsw,
                            const float* __restrict__ bias,
                            float* __restrict__ outf, unsigned short* __restrict__ outb,
                            int M, int relu) {
    int tid = threadIdx.x;
    int wid = tid >> 6, lane = tid & 63;
    int lr = lane & 15, lg = lane >> 4;
    int r0 = blockIdx.x * 64;
    int c0 = wid * 64;
    f32x4 acc[4][4] = {};
    #pragma unroll 2
    for (int k0 = 0; k0 < 512; k0 += 32) {
        bf16x8 a[4];
        #pragma unroll
        for (int mf = 0; mf < 4; ++mf)
            a[mf] = *(const bf16x8*)(X + (size_t)(r0 + mf * 16 + lr) * 512 + k0 + lg * 8);
        #pragma unroll
        for (int nf = 0; nf < 4; ++nf) {
            bf16x8 b = *(const bf16x8*)(Wsw + ((size_t)(k0 >> 3) + lg) * 2048 +
                                        (size_t)(c0 + nf * 16 + lr) * 8);
            #pragma unroll
            for (int mf = 0; mf < 4; ++mf)
                acc[mf][nf] = __builtin_amdgcn_mfma_f32_16x16x32_bf16(a[mf], b, acc[mf][nf], 0, 0, 0);
        }
    }
    #pragma unroll
    for (int nf = 0; nf < 4; ++nf) {
        int col = c0 + nf * 16 + lr;
        float bv = bias[col];
        #pragma unroll
        for (int mf = 0; mf < 4; ++mf) {
            #pragma unroll
            for (int j = 0; j < 4; ++j) {
                int row = r0 + mf * 16 + lg * 4 + j;
                if (row < M) {
                    float v = acc[mf][nf][j] + bv;
                    if (relu) v = fmaxf(v, 0.0f);
                    size_t idx = (size_t)row * 256 + col;
                    if (outf) outf[idx] = v;
                    else      outb[idx] = f2bf(v);
                }
            }
        }
    }
}

extern "C" void kernel_launch(void* const* d_in, const int* in_sizes, int n_in,
                              void* d_out, int out_size, void* d_ws, size_t ws_size,
                              hipStream_t stream) {
    const float* x  = (const float*)d_in[0];
    const int*   e0 = (const int*)d_in[1];
    const int*   e1 = (const int*)d_in[2];
    const int*   e2 = (const int*)d_in[3];
    const float* Wl[3] = {(const float*)d_in[4], (const float*)d_in[7], (const float*)d_in[10]};
    const float* bl[3] = {(const float*)d_in[5], (const float*)d_in[8], (const float*)d_in[11]};
    const float* Wr[3] = {(const float*)d_in[6], (const float*)d_in[9], (const float*)d_in[12]};
    float* out = (float*)d_out;

    char* ws = (char*)d_ws;
    unsigned short* X      = (unsigned short*)(ws + 0);            // 50048*512*2 = 51,249,152
    unsigned short* xb     = (unsigned short*)(ws + 51249152);     // 100000*256*2 = 51,200,000
    unsigned short* h1b    = (unsigned short*)(ws + 102449152);    //  50000*256*2 = 25,600,000
    unsigned short* h2b    = (unsigned short*)(ws + 128049152);    //  25000*256*2 = 12,800,000
    unsigned short* Wsw    = (unsigned short*)(ws + 140849152);    //  3*512*256*2 =    786,432
    int*            cnt    = (int*)(ws + 141635584);               //    200,192
    int*            rowptr = (int*)(ws + 141835776);               //    200,192
    int*            cursor = (int*)(ws + 142035968);               //    200,192
    int*            eids   = (int*)(ws + 142236160);               //  3,200,000

    const int Ns[4] = {100000, 50000, 25000, 12500};
    const int Es[3] = {800000, 400000, 200000};
    const int* eidx[3] = {e0, e1, e2};
    const unsigned short* hsrc[3] = {xb, h1b, h2b};

    cvt_kernel<<<(6400000 + 255) / 256, 256, 0, stream>>>(x, xb, 6400000);
    convw_kernel<<<1536, 256, 0, stream>>>(Wl[0], Wr[0], Wl[1], Wr[1], Wl[2], Wr[2], Wsw);

    for (int l = 0; l < 3; ++l) {
        int Md = Ns[l + 1], E = Es[l];
        int Mpad = (Md + 63) & ~63;
        int eb = (E + 255) / 256;
        hipMemsetAsync(cnt, 0, (size_t)Md * 4, stream);
        hist_kernel<<<eb, 256, 0, stream>>>(eidx[l], E, cnt);
        scan_kernel<<<1, 1024, 0, stream>>>(cnt, rowptr, cursor, Md, E);
        fill_kernel<<<eb, 256, 0, stream>>>(eidx[l], E, cursor, eids);
        agg_pack_kernel<<<Mpad / 4, 256, 0, stream>>>(hsrc[l], rowptr, eids, Md, Mpad, X);
        float* of = (l == 2) ? out : nullptr;
        unsigned short* ob = (l == 0) ? h1b : (l == 1) ? h2b : nullptr;
        gemm_kernel<<<Mpad / 64, 256, 0, stream>>>(
            X, Wsw + (size_t)l * 131072, bl[l], of, ob, Md, (l < 2) ? 1 : 0);
    }
}

// Round 4
// 586.703 us; speedup vs baseline: 8.5853x; 1.2957x over previous
//
#include <hip/hip_runtime.h>
#include <hip/hip_bf16.h>

typedef __attribute__((ext_vector_type(8))) short bf16x8;
typedef __attribute__((ext_vector_type(4))) float f32x4;

__device__ inline unsigned short f2bf(float f) {
    union { float f; unsigned u; } v; v.f = f;
    unsigned r = v.u + 0x7fff + ((v.u >> 16) & 1);   // RNE
    return (unsigned short)(r >> 16);
}
__device__ inline float bf2f(unsigned short u) {
    union { unsigned u; float f; } v; v.u = (unsigned)u << 16;
    return v.f;
}

// Segment geometry (all layers batched). Padded to 256-multiples.
#define SEG0_OFF 0
#define SEG1_OFF 50176
#define SEG2_OFF 75264
#define SEG_TOT  87808
#define NB0 196
#define NB1 98
#define NB2 49
#define NB_TOT 343
#define E_TOT 1400000

__constant__ const int c_segoff[3] = {SEG0_OFF, SEG1_OFF, SEG2_OFF};
__constant__ const int c_segM[3]   = {50000, 25000, 12500};
__constant__ const int c_Es[3]     = {800000, 400000, 200000};
__constant__ const int c_eoff[3]   = {0, 800000, 1200000};

// fp32 -> bf16 bulk convert (x -> xb), float4/thread.
__global__ void cvt_kernel(const float* __restrict__ x, unsigned short* __restrict__ xb, int n4) {
    int i = blockIdx.x * blockDim.x + threadIdx.x;
    if (i >= n4) return;
    float4 v = ((const float4*)x)[i];
    ushort4 o = { f2bf(v.x), f2bf(v.y), f2bf(v.z), f2bf(v.w) };
    ((ushort4*)xb)[i] = o;
}

// --- Batched CSR build (all 3 layers) ---------------------------------------

__global__ void hist_all_kernel(const int* __restrict__ e0, const int* __restrict__ e1,
                                const int* __restrict__ e2, int* __restrict__ cnt) {
    int e = blockIdx.x * blockDim.x + threadIdx.x;
    if (e >= E_TOT) return;
    int l, el; const int* ex;
    if (e < 800000)       { l = 0; el = e;           ex = e0; }
    else if (e < 1200000) { l = 1; el = e - 800000;  ex = e1; }
    else                  { l = 2; el = e - 1200000; ex = e2; }
    int d = ex[c_Es[l] + el];
    atomicAdd(&cnt[c_segoff[l] + d], 1);
}

__device__ inline void seg_of_block(int b, int& seg, int& lb) {
    if (b < NB0)            { seg = 0; lb = b; }
    else if (b < NB0 + NB1) { seg = 1; lb = b - NB0; }
    else                    { seg = 2; lb = b - NB0 - NB1; }
}

// Per-256-chunk sums.
__global__ void partial_kernel(const int* __restrict__ cnt, int* __restrict__ bsum) {
    int seg, lb; seg_of_block(blockIdx.x, seg, lb);
    __shared__ int sh[256];
    int t = threadIdx.x;
    sh[t] = cnt[c_segoff[seg] + lb * 256 + t];
    __syncthreads();
    #pragma unroll
    for (int off = 128; off > 0; off >>= 1) {
        if (t < off) sh[t] += sh[t + off];
        __syncthreads();
    }
    if (t == 0) bsum[seg * 256 + lb] = sh[0];
}

// Exclusive scan of each segment's block sums (<=196 each); also rowptr[M]=E.
__global__ void scanb_kernel(int* __restrict__ bsum, int* __restrict__ rowptr) {
    const int nb[3] = {NB0, NB1, NB2};
    int s = blockIdx.x, t = threadIdx.x;
    __shared__ int sh[256];
    int v = (t < nb[s]) ? bsum[s * 256 + t] : 0;
    sh[t] = v;
    __syncthreads();
    #pragma unroll
    for (int off = 1; off < 256; off <<= 1) {
        int u = (t >= off) ? sh[t - off] : 0;
        __syncthreads();
        sh[t] += u;
        __syncthreads();
    }
    if (t < nb[s]) bsum[s * 256 + t] = sh[t] - v;   // exclusive
    if (t == 0) rowptr[c_segoff[s] + c_segM[s]] = c_Es[s];
}

// Block-local exclusive scan + scanned block offset -> rowptr/cursor.
__global__ void emit_kernel(const int* __restrict__ cnt, const int* __restrict__ bsum,
                            int* __restrict__ rowptr, int* __restrict__ cursor) {
    int seg, lb; seg_of_block(blockIdx.x, seg, lb);
    __shared__ int sh[256];
    int t = threadIdx.x;
    int li = lb * 256 + t;
    int idx = c_segoff[seg] + li;
    int v = cnt[idx];
    sh[t] = v;
    __syncthreads();
    #pragma unroll
    for (int off = 1; off < 256; off <<= 1) {
        int u = (t >= off) ? sh[t - off] : 0;
        __syncthreads();
        sh[t] += u;
        __syncthreads();
    }
    int excl = sh[t] - v + bsum[seg * 256 + lb];
    if (li < c_segM[seg]) { rowptr[idx] = excl; cursor[idx] = excl; }
}

__global__ void fill_all_kernel(const int* __restrict__ e0, const int* __restrict__ e1,
                                const int* __restrict__ e2,
                                int* __restrict__ cursor, int* __restrict__ eids) {
    int e = blockIdx.x * blockDim.x + threadIdx.x;
    if (e >= E_TOT) return;
    int l, el; const int* ex;
    if (e < 800000)       { l = 0; el = e;           ex = e0; }
    else if (e < 1200000) { l = 1; el = e - 800000;  ex = e1; }
    else                  { l = 2; el = e - 1200000; ex = e2; }
    int d = ex[c_Es[l] + el];
    int pos = atomicAdd(&cursor[c_segoff[l] + d], 1);
    eids[c_eoff[l] + pos] = ex[el];
}

// --- Aggregate (mean over CSR neighbors, bf16 rows) + pack [mean | h_dst] ----
// One wave per dst row; 64 lanes x ushort4 (8B) = full 256-col bf16 row.
__global__ void agg_pack_kernel(const unsigned short* __restrict__ hb,
                                const int* __restrict__ rowptr,
                                const int* __restrict__ eids,
                                int M, int Mpad,
                                unsigned short* __restrict__ X) {
    int lane = threadIdx.x & 63;
    int row = blockIdx.x * (blockDim.x >> 6) + (threadIdx.x >> 6);
    if (row >= Mpad) return;
    ushort4* Xv = (ushort4*)X;
    const ushort4* hv = (const ushort4*)hb;
    if (row >= M) {
        ushort4 z = {0, 0, 0, 0};
        Xv[(size_t)row * 128 + lane] = z;
        Xv[(size_t)row * 128 + 64 + lane] = z;
        return;
    }
    int beg = rowptr[row], end = rowptr[row + 1];
    float a0 = 0, a1 = 0, a2 = 0, a3 = 0;
    float b0 = 0, b1 = 0, b2 = 0, b3 = 0;
    int j = beg;
    for (; j + 4 <= end; j += 4) {
        int i0 = eids[j], i1 = eids[j + 1], i2 = eids[j + 2], i3 = eids[j + 3];
        ushort4 v0 = hv[(size_t)i0 * 64 + lane];
        ushort4 v1 = hv[(size_t)i1 * 64 + lane];
        ushort4 v2 = hv[(size_t)i2 * 64 + lane];
        ushort4 v3 = hv[(size_t)i3 * 64 + lane];
        a0 += bf2f(v0.x) + bf2f(v2.x); a1 += bf2f(v0.y) + bf2f(v2.y);
        a2 += bf2f(v0.z) + bf2f(v2.z); a3 += bf2f(v0.w) + bf2f(v2.w);
        b0 += bf2f(v1.x) + bf2f(v3.x); b1 += bf2f(v1.y) + bf2f(v3.y);
        b2 += bf2f(v1.z) + bf2f(v3.z); b3 += bf2f(v1.w) + bf2f(v3.w);
    }
    for (; j < end; ++j) {
        ushort4 v = hv[(size_t)eids[j] * 64 + lane];
        a0 += bf2f(v.x); a1 += bf2f(v.y); a2 += bf2f(v.z); a3 += bf2f(v.w);
    }
    float inv = 1.0f / fmaxf((float)(end - beg), 1.0f);
    ushort4 m;
    m.x = f2bf((a0 + b0) * inv); m.y = f2bf((a1 + b1) * inv);
    m.z = f2bf((a2 + b2) * inv); m.w = f2bf((a3 + b3) * inv);
    Xv[(size_t)row * 128 + lane] = m;
    Xv[(size_t)row * 128 + 64 + lane] = hv[(size_t)row * 64 + lane];
}

// Repack [W_l;W_r] (fp32 [512][256] concat) -> bf16 fragment layout
// Wsw[kb][col][e]  (kb = k/8, e = k%8): a B-fragment is one 16B load.
__global__ void convw_kernel(const float* __restrict__ Wl0, const float* __restrict__ Wr0,
                             const float* __restrict__ Wl1, const float* __restrict__ Wr1,
                             const float* __restrict__ Wl2, const float* __restrict__ Wr2,
                             unsigned short* __restrict__ Wsw) {
    int gid = blockIdx.x * blockDim.x + threadIdx.x;   // 3 * 512 * 256
    int l = gid >> 17;
    int r = gid & 131071;
    int k = r >> 8, c = r & 255;
    const float* W;
    if (k < 256) W = (l == 0) ? Wl0 : (l == 1) ? Wl1 : Wl2;
    else         W = (l == 0) ? Wr0 : (l == 1) ? Wr1 : Wr2;
    float v = W[(size_t)(k & 255) * 256 + c];
    Wsw[(size_t)l * 131072 + (size_t)(k >> 3) * 2048 + c * 8 + (k & 7)] = f2bf(v);
}

// out[M][256] = X[M][512] @ Wcat[512][256] + bias (+ReLU).
// Block 256 thr = 4 waves; block tile 64(M) x 256(N); wave tile 64 x 64.
__global__ void gemm_kernel(const unsigned short* __restrict__ X,
                            const unsigned short* __restrict__ Wsw,
                            const float* __restrict__ bias,
                            float* __restrict__ outf, unsigned short* __restrict__ outb,
                            int M, int relu) {
    int tid = threadIdx.x;
    int wid = tid >> 6, lane = tid & 63;
    int lr = lane & 15, lg = lane >> 4;
    int r0 = blockIdx.x * 64;
    int c0 = wid * 64;
    f32x4 acc[4][4] = {};
    #pragma unroll 2
    for (int k0 = 0; k0 < 512; k0 += 32) {
        bf16x8 a[4];
        #pragma unroll
        for (int mf = 0; mf < 4; ++mf)
            a[mf] = *(const bf16x8*)(X + (size_t)(r0 + mf * 16 + lr) * 512 + k0 + lg * 8);
        #pragma unroll
        for (int nf = 0; nf < 4; ++nf) {
            bf16x8 b = *(const bf16x8*)(Wsw + ((size_t)(k0 >> 3) + lg) * 2048 +
                                        (size_t)(c0 + nf * 16 + lr) * 8);
            #pragma unroll
            for (int mf = 0; mf < 4; ++mf)
                acc[mf][nf] = __builtin_amdgcn_mfma_f32_16x16x32_bf16(a[mf], b, acc[mf][nf], 0, 0, 0);
        }
    }
    #pragma unroll
    for (int nf = 0; nf < 4; ++nf) {
        int col = c0 + nf * 16 + lr;
        float bv = bias[col];
        #pragma unroll
        for (int mf = 0; mf < 4; ++mf) {
            #pragma unroll
            for (int j = 0; j < 4; ++j) {
                int row = r0 + mf * 16 + lg * 4 + j;
                if (row < M) {
                    float v = acc[mf][nf][j] + bv;
                    if (relu) v = fmaxf(v, 0.0f);
                    size_t idx = (size_t)row * 256 + col;
                    if (outf) outf[idx] = v;
                    else      outb[idx] = f2bf(v);
                }
            }
        }
    }
}

extern "C" void kernel_launch(void* const* d_in, const int* in_sizes, int n_in,
                              void* d_out, int out_size, void* d_ws, size_t ws_size,
                              hipStream_t stream) {
    const float* x  = (const float*)d_in[0];
    const int*   e0 = (const int*)d_in[1];
    const int*   e1 = (const int*)d_in[2];
    const int*   e2 = (const int*)d_in[3];
    const float* Wl[3] = {(const float*)d_in[4], (const float*)d_in[7], (const float*)d_in[10]};
    const float* bl[3] = {(const float*)d_in[5], (const float*)d_in[8], (const float*)d_in[11]};
    const float* Wr[3] = {(const float*)d_in[6], (const float*)d_in[9], (const float*)d_in[12]};
    float* out = (float*)d_out;

    char* ws = (char*)d_ws;
    unsigned short* X      = (unsigned short*)(ws + 0);            // 50048*512*2 = 51,249,152
    unsigned short* xb     = (unsigned short*)(ws + 51249152);     // 100000*256*2 = 51,200,000
    unsigned short* h1b    = (unsigned short*)(ws + 102449152);    //  50000*256*2 = 25,600,000
    unsigned short* h2b    = (unsigned short*)(ws + 128049152);    //  25000*256*2 = 12,800,000
    unsigned short* Wsw    = (unsigned short*)(ws + 140849152);    //  3*512*256*2 =    786,432
    int*            cnt    = (int*)(ws + 141635584);               // 87808*4 = 351,232
    int*            rowptr = (int*)(ws + 141986816);               // 351,232
    int*            cursor = (int*)(ws + 142338048);               // 351,232
    int*            bsum   = (int*)(ws + 142689280);               // 768*4 = 3,072 (pad 4096)
    int*            eids   = (int*)(ws + 142693376);               // 1,400,000*4 = 5,600,000

    const int Ns[4] = {100000, 50000, 25000, 12500};
    const int segoff[3] = {SEG0_OFF, SEG1_OFF, SEG2_OFF};
    const int eoff[3] = {0, 800000, 1200000};
    const unsigned short* hsrc[3] = {xb, h1b, h2b};

    hipMemsetAsync(cnt, 0, (size_t)SEG_TOT * 4, stream);
    cvt_kernel<<<(6400000 + 255) / 256, 256, 0, stream>>>(x, xb, 6400000);
    convw_kernel<<<1536, 256, 0, stream>>>(Wl[0], Wr[0], Wl[1], Wr[1], Wl[2], Wr[2], Wsw);

    hist_all_kernel<<<(E_TOT + 255) / 256, 256, 0, stream>>>(e0, e1, e2, cnt);
    partial_kernel<<<NB_TOT, 256, 0, stream>>>(cnt, bsum);
    scanb_kernel<<<3, 256, 0, stream>>>(bsum, rowptr);
    emit_kernel<<<NB_TOT, 256, 0, stream>>>(cnt, bsum, rowptr, cursor);
    fill_all_kernel<<<(E_TOT + 255) / 256, 256, 0, stream>>>(e0, e1, e2, cursor, eids);

    for (int l = 0; l < 3; ++l) {
        int Md = Ns[l + 1];
        int Mpad = (Md + 63) & ~63;
        agg_pack_kernel<<<Mpad / 4, 256, 0, stream>>>(
            hsrc[l], rowptr + segoff[l], eids + eoff[l], Md, Mpad, X);
        float* of = (l == 2) ? out : nullptr;
        unsigned short* ob = (l == 0) ? h1b : (l == 1) ? h2b : nullptr;
        gemm_kernel<<<Mpad / 64, 256, 0, stream>>>(
            X, Wsw + (size_t)l * 131072, bl[l], of, ob, Md, (l < 2) ? 1 : 0);
    }
}

// Round 7
// 499.589 us; speedup vs baseline: 10.0823x; 1.1744x over previous
//
#include <hip/hip_runtime.h>
#include <hip/hip_bf16.h>

typedef __attribute__((ext_vector_type(8))) short bf16x8;
typedef __attribute__((ext_vector_type(4))) float f32x4;

__device__ inline unsigned short f2bf(float f) {
    union { float f; unsigned u; } v; v.f = f;
    unsigned r = v.u + 0x7fff + ((v.u >> 16) & 1);   // RNE
    return (unsigned short)(r >> 16);
}
__device__ inline float bf2f(unsigned short u) {
    union { unsigned u; float f; } v; v.u = (unsigned)u << 16;
    return v.f;
}

// Segment geometry (all layers batched). Padded to 256-multiples.
#define SEG0_OFF 0
#define SEG1_OFF 50176
#define SEG2_OFF 75264
#define SEG_TOT  87808
#define NB0 196
#define NB1 98
#define NB2 49
#define NB_TOT 343
#define E_TOT 1400000
#define CVT_NB 25000     // 25,600,000 floats = 6,400,000 float4 / 256 thr (1 float4/thr)
#define CONVW_NB 1536    // 3*512*256 / 256
#define HIST_NB 5469     // ceil(1,400,000 / 256)

__constant__ const int c_segoff[3] = {SEG0_OFF, SEG1_OFF, SEG2_OFF};
__constant__ const int c_segM[3]   = {50000, 25000, 12500};
__constant__ const int c_Es[3]     = {800000, 400000, 200000};
__constant__ const int c_eoff[3]   = {0, 800000, 1200000};

// Fused prologue: [0,CVT_NB) fp32->bf16 convert of x; [CVT_NB,+CONVW_NB) weight
// repack; rest: dst histogram with per-edge rank capture (atomicAdd old value).
// All three are independent; fusing co-schedules BW-bound cvt with
// atomic-latency-bound hist.
__global__ void prep_kernel(const float* __restrict__ x, unsigned short* __restrict__ xb,
                            const float* __restrict__ Wl0, const float* __restrict__ Wr0,
                            const float* __restrict__ Wl1, const float* __restrict__ Wr1,
                            const float* __restrict__ Wl2, const float* __restrict__ Wr2,
                            unsigned short* __restrict__ Wsw,
                            const int* __restrict__ e0, const int* __restrict__ e1,
                            const int* __restrict__ e2,
                            int* __restrict__ cnt, unsigned short* __restrict__ rank) {
    int b = blockIdx.x, t = threadIdx.x;
    if (b < CVT_NB) {
        int i = b * 256 + t;
        float4 v = ((const float4*)x)[i];
        ushort4 o = { f2bf(v.x), f2bf(v.y), f2bf(v.z), f2bf(v.w) };
        ((ushort4*)xb)[i] = o;
    } else if (b < CVT_NB + CONVW_NB) {
        int gid = (b - CVT_NB) * 256 + t;      // 3 * 512 * 256
        int l = gid >> 17;
        int r = gid & 131071;
        int k = r >> 8, c = r & 255;
        const float* W;
        if (k < 256) W = (l == 0) ? Wl0 : (l == 1) ? Wl1 : Wl2;
        else         W = (l == 0) ? Wr0 : (l == 1) ? Wr1 : Wr2;
        float v = W[(size_t)(k & 255) * 256 + c];
        Wsw[(size_t)l * 131072 + (size_t)(k >> 3) * 2048 + c * 8 + (k & 7)] = f2bf(v);
    } else {
        int e = (b - CVT_NB - CONVW_NB) * 256 + t;
        if (e >= E_TOT) return;
        int l, el; const int* ex;
        if (e < 800000)       { l = 0; el = e;           ex = e0; }
        else if (e < 1200000) { l = 1; el = e - 800000;  ex = e1; }
        else                  { l = 2; el = e - 1200000; ex = e2; }
        int d = ex[c_Es[l] + el];
        int r = atomicAdd(&cnt[c_segoff[l] + d], 1);
        rank[e] = (unsigned short)r;
    }
}

__device__ inline void seg_of_block(int b, int& seg, int& lb) {
    if (b < NB0)            { seg = 0; lb = b; }
    else if (b < NB0 + NB1) { seg = 1; lb = b - NB0; }
    else                    { seg = 2; lb = b - NB0 - NB1; }
}

// Per-256-chunk sums.
__global__ void partial_kernel(const int* __restrict__ cnt, int* __restrict__ bsum) {
    int seg, lb; seg_of_block(blockIdx.x, seg, lb);
    __shared__ int sh[256];
    int t = threadIdx.x;
    sh[t] = cnt[c_segoff[seg] + lb * 256 + t];
    __syncthreads();
    #pragma unroll
    for (int off = 128; off > 0; off >>= 1) {
        if (t < off) sh[t] += sh[t + off];
        __syncthreads();
    }
    if (t == 0) bsum[seg * 256 + lb] = sh[0];
}

// Exclusive scan of each segment's block sums (<=196 each); also rowptr[M]=E.
__global__ void scanb_kernel(int* __restrict__ bsum, int* __restrict__ rowptr) {
    const int nb[3] = {NB0, NB1, NB2};
    int s = blockIdx.x, t = threadIdx.x;
    __shared__ int sh[256];
    int v = (t < nb[s]) ? bsum[s * 256 + t] : 0;
    sh[t] = v;
    __syncthreads();
    #pragma unroll
    for (int off = 1; off < 256; off <<= 1) {
        int u = (t >= off) ? sh[t - off] : 0;
        __syncthreads();
        sh[t] += u;
        __syncthreads();
    }
    if (t < nb[s]) bsum[s * 256 + t] = sh[t] - v;   // exclusive
    if (t == 0) rowptr[c_segoff[s] + c_segM[s]] = c_Es[s];
}

// Block-local exclusive scan + scanned block offset -> rowptr.
__global__ void emit_kernel(const int* __restrict__ cnt, const int* __restrict__ bsum,
                            int* __restrict__ rowptr) {
    int seg, lb; seg_of_block(blockIdx.x, seg, lb);
    __shared__ int sh[256];
    int t = threadIdx.x;
    int li = lb * 256 + t;
    int idx = c_segoff[seg] + li;
    int v = cnt[idx];
    sh[t] = v;
    __syncthreads();
    #pragma unroll
    for (int off = 1; off < 256; off <<= 1) {
        int u = (t >= off) ? sh[t - off] : 0;
        __syncthreads();
        sh[t] += u;
        __syncthreads();
    }
    int excl = sh[t] - v + bsum[seg * 256 + lb];
    if (li < c_segM[seg]) rowptr[idx] = excl;
}

// Atomic-free CSR fill: pos = rowptr[dst] + rank[e].
__global__ void fill_all_kernel(const int* __restrict__ e0, const int* __restrict__ e1,
                                const int* __restrict__ e2,
                                const int* __restrict__ rowptr,
                                const unsigned short* __restrict__ rank,
                                int* __restrict__ eids) {
    int e = blockIdx.x * blockDim.x + threadIdx.x;
    if (e >= E_TOT) return;
    int l, el; const int* ex;
    if (e < 800000)       { l = 0; el = e;           ex = e0; }
    else if (e < 1200000) { l = 1; el = e - 800000;  ex = e1; }
    else                  { l = 2; el = e - 1200000; ex = e2; }
    int d = ex[c_Es[l] + el];
    int pos = rowptr[c_segoff[l] + d] + (int)rank[e];
    eids[c_eoff[l] + pos] = ex[el];
}

// --- Aggregate (mean over CSR neighbors, bf16 rows) + pack [mean | h_dst] ----
// One wave per dst row; 64 lanes x ushort4 (8B) = full 256-col bf16 row.
__global__ void agg_pack_kernel(const unsigned short* __restrict__ hb,
                                const int* __restrict__ rowptr,
                                const int* __restrict__ eids,
                                int M, int Mpad,
                                unsigned short* __restrict__ X) {
    int lane = threadIdx.x & 63;
    int row = blockIdx.x * (blockDim.x >> 6) + (threadIdx.x >> 6);
    if (row >= Mpad) return;
    ushort4* Xv = (ushort4*)X;
    const ushort4* hv = (const ushort4*)hb;
    if (row >= M) {
        ushort4 z = {0, 0, 0, 0};
        Xv[(size_t)row * 128 + lane] = z;
        Xv[(size_t)row * 128 + 64 + lane] = z;
        return;
    }
    int beg = rowptr[row], end = rowptr[row + 1];
    float a0 = 0, a1 = 0, a2 = 0, a3 = 0;
    float b0 = 0, b1 = 0, b2 = 0, b3 = 0;
    int j = beg;
    for (; j + 4 <= end; j += 4) {
        int i0 = eids[j], i1 = eids[j + 1], i2 = eids[j + 2], i3 = eids[j + 3];
        ushort4 v0 = hv[(size_t)i0 * 64 + lane];
        ushort4 v1 = hv[(size_t)i1 * 64 + lane];
        ushort4 v2 = hv[(size_t)i2 * 64 + lane];
        ushort4 v3 = hv[(size_t)i3 * 64 + lane];
        a0 += bf2f(v0.x) + bf2f(v2.x); a1 += bf2f(v0.y) + bf2f(v2.y);
        a2 += bf2f(v0.z) + bf2f(v2.z); a3 += bf2f(v0.w) + bf2f(v2.w);
        b0 += bf2f(v1.x) + bf2f(v3.x); b1 += bf2f(v1.y) + bf2f(v3.y);
        b2 += bf2f(v1.z) + bf2f(v3.z); b3 += bf2f(v1.w) + bf2f(v3.w);
    }
    for (; j < end; ++j) {
        ushort4 v = hv[(size_t)eids[j] * 64 + lane];
        a0 += bf2f(v.x); a1 += bf2f(v.y); a2 += bf2f(v.z); a3 += bf2f(v.w);
    }
    float inv = 1.0f / fmaxf((float)(end - beg), 1.0f);
    ushort4 m;
    m.x = f2bf((a0 + b0) * inv); m.y = f2bf((a1 + b1) * inv);
    m.z = f2bf((a2 + b2) * inv); m.w = f2bf((a3 + b3) * inv);
    Xv[(size_t)row * 128 + lane] = m;
    Xv[(size_t)row * 128 + 64 + lane] = hv[(size_t)row * 64 + lane];
}

// out[M][256] = X[M][512] @ Wcat[512][256] + bias (+ReLU).
// Block 256 thr = 4 waves; block tile 64(M) x 256(N); wave tile 64 x 64.
__global__ void gemm_kernel(const unsigned short* __restrict__ X,
                            const unsigned short* __restrict__ Wsw,
                            const float* __restrict__ bias,
                            float* __restrict__ outf, unsigned short* __restrict__ outb,
                            int M, int relu) {
    int tid = threadIdx.x;
    int wid = tid >> 6, lane = tid & 63;
    int lr = lane & 15, lg = lane >> 4;
    int r0 = blockIdx.x * 64;
    int c0 = wid * 64;
    f32x4 acc[4][4] = {};
    #pragma unroll 2
    for (int k0 = 0; k0 < 512; k0 += 32) {
        bf16x8 a[4];
        #pragma unroll
        for (int mf = 0; mf < 4; ++mf)
            a[mf] = *(const bf16x8*)(X + (size_t)(r0 + mf * 16 + lr) * 512 + k0 + lg * 8);
        #pragma unroll
        for (int nf = 0; nf < 4; ++nf) {
            bf16x8 b = *(const bf16x8*)(Wsw + ((size_t)(k0 >> 3) + lg) * 2048 +
                                        (size_t)(c0 + nf * 16 + lr) * 8);
            #pragma unroll
            for (int mf = 0; mf < 4; ++mf)
                acc[mf][nf] = __builtin_amdgcn_mfma_f32_16x16x32_bf16(a[mf], b, acc[mf][nf], 0, 0, 0);
        }
    }
    #pragma unroll
    for (int nf = 0; nf < 4; ++nf) {
        int col = c0 + nf * 16 + lr;
        float bv = bias[col];
        #pragma unroll
        for (int mf = 0; mf < 4; ++mf) {
            #pragma unroll
            for (int j = 0; j < 4; ++j) {
                int row = r0 + mf * 16 + lg * 4 + j;
                if (row < M) {
                    float v = acc[mf][nf][j] + bv;
                    if (relu) v = fmaxf(v, 0.0f);
                    size_t idx = (size_t)row * 256 + col;
                    if (outf) outf[idx] = v;
                    else      outb[idx] = f2bf(v);
                }
            }
        }
    }
}

extern "C" void kernel_launch(void* const* d_in, const int* in_sizes, int n_in,
                              void* d_out, int out_size, void* d_ws, size_t ws_size,
                              hipStream_t stream) {
    const float* x  = (const float*)d_in[0];
    const int*   e0 = (const int*)d_in[1];
    const int*   e1 = (const int*)d_in[2];
    const int*   e2 = (const int*)d_in[3];
    const float* Wl[3] = {(const float*)d_in[4], (const float*)d_in[7], (const float*)d_in[10]};
    const float* bl[3] = {(const float*)d_in[5], (const float*)d_in[8], (const float*)d_in[11]};
    const float* Wr[3] = {(const float*)d_in[6], (const float*)d_in[9], (const float*)d_in[12]};
    float* out = (float*)d_out;

    char* ws = (char*)d_ws;
    unsigned short* X      = (unsigned short*)(ws + 0);            // 50048*512*2 = 51,249,152
    unsigned short* rank   = (unsigned short*)(ws + 45000000);     // 2.8MB, aliases X tail:
                                                                   // rank dead before agg0 writes X
    unsigned short* xb     = (unsigned short*)(ws + 51249152);     // 100000*256*2 = 51,200,000
    unsigned short* h1b    = (unsigned short*)(ws + 102449152);    //  50000*256*2 = 25,600,000
    unsigned short* h2b    = (unsigned short*)(ws + 128049152);    //  25000*256*2 = 12,800,000
    unsigned short* Wsw    = (unsigned short*)(ws + 140849152);    //  3*512*256*2 =    786,432
    int*            cnt    = (int*)(ws + 141635584);               // 87808*4 = 351,232
    int*            rowptr = (int*)(ws + 141986816);               // 351,232
    int*            bsum   = (int*)(ws + 142338048);               // 4,096
    int*            eids   = (int*)(ws + 142342144);               // 5,600,000 -> ends 147,942,144

    const int Ns[4] = {100000, 50000, 25000, 12500};
    const int segoff[3] = {SEG0_OFF, SEG1_OFF, SEG2_OFF};
    const int eoff[3] = {0, 800000, 1200000};
    const unsigned short* hsrc[3] = {xb, h1b, h2b};

    hipMemsetAsync(cnt, 0, (size_t)SEG_TOT * 4, stream);
    prep_kernel<<<CVT_NB + CONVW_NB + HIST_NB, 256, 0, stream>>>(
        x, xb, Wl[0], Wr[0], Wl[1], Wr[1], Wl[2], Wr[2], Wsw, e0, e1, e2, cnt, rank);
    partial_kernel<<<NB_TOT, 256, 0, stream>>>(cnt, bsum);
    scanb_kernel<<<3, 256, 0, stream>>>(bsum, rowptr);
    emit_kernel<<<NB_TOT, 256, 0, stream>>>(cnt, bsum, rowptr);
    fill_all_kernel<<<(E_TOT + 255) / 256, 256, 0, stream>>>(e0, e1, e2, rowptr, rank, eids);

    for (int l = 0; l < 3; ++l) {
        int Md = Ns[l + 1];
        int Mpad = (Md + 63) & ~63;
        agg_pack_kernel<<<Mpad / 4, 256, 0, stream>>>(
            hsrc[l], rowptr + segoff[l], eids + eoff[l], Md, Mpad, X);
        float* of = (l == 2) ? out : nullptr;
        unsigned short* ob = (l == 0) ? h1b : (l == 1) ? h2b : nullptr;
        gemm_kernel<<<Mpad / 64, 256, 0, stream>>>(
            X, Wsw + (size_t)l * 131072, bl[l], of, ob, Md, (l < 2) ? 1 : 0);
    }
}